// Round 7
// baseline (1083.263 us; speedup 1.0000x reference)
//
#include <hip/hip_runtime.h>
#include <math.h>

// Problem constants (from reference)
#define T_WIN   3
#define N_NODES 50000
#define HID     128
#define E_PER_T 100000
#define NH      8
#define DK      16
#define CAP     64   // per-node LDS logit cache (avg total degree ~6; slow path covers overflow)

// R11: ffn traffic STILL 2.3x ideal (FETCH 522 = 230 reads + ~292 weight-miss,
// WRITE 586 = 230 out + L2 write-allocate churn). Cause: streaming hat/x/out
// flows through L2 and evicts the 128KB weight set (4689 blocks x 128KB = up
// to 600MB refetch). Fix: nontemporal loads for hat/x, nontemporal stores for
// out and attn's hat writes -> L2 reserved for weights. No arithmetic change.

typedef unsigned short u16;
typedef __attribute__((ext_vector_type(8))) short bf16x8;   // 8 bf16 = 4 VGPR
typedef __attribute__((ext_vector_type(4))) float f32x4;
typedef __attribute__((ext_vector_type(2))) float f32x2;

__device__ __forceinline__ u16 f2bf(float v) {              // RNE f32->bf16
    unsigned u = __float_as_uint(v);
    return (u16)((u + 0x7fffu + ((u >> 16) & 1u)) >> 16);
}
__device__ __forceinline__ float bf2f(u16 u) {
    return __uint_as_float(((unsigned)u) << 16);
}
__device__ __forceinline__ f32x4 mfma16(bf16x8 a, bf16x8 b, f32x4 c) {
    return __builtin_amdgcn_mfma_f32_16x16x32_bf16(a, b, c, 0, 0, 0);
}
__device__ __forceinline__ f32x4 ntload4(const float* p) {
    return __builtin_nontemporal_load((const f32x4*)p);
}
__device__ __forceinline__ void ntstore4(float* p, f32x4 v) {
    __builtin_nontemporal_store(v, (f32x4*)p);
}
__device__ __forceinline__ void ntstore2(float* p, f32x2 v) {
    __builtin_nontemporal_store(v, (f32x2*)p);
}

// ---------------------------------------------------------------------------
// Weight prep, ONE dispatch. y=0..2: hi/lo split of Wq/Wk/Wv (128x128);
// y=3: W1 (128x256) bf16; y=4: W2 (256x128) bf16. dst layout [C][R].
// ---------------------------------------------------------------------------
__global__ __launch_bounds__(256) void wprep_kernel(
    const float* __restrict__ Wq, const float* __restrict__ Wk,
    const float* __restrict__ Wv, const float* __restrict__ W1,
    const float* __restrict__ W2,
    u16* __restrict__ WqTh, u16* __restrict__ WqTl,
    u16* __restrict__ WkTh, u16* __restrict__ WkTl,
    u16* __restrict__ WvTh, u16* __restrict__ WvTl,
    u16* __restrict__ W1T, u16* __restrict__ W2T)
{
    const int y = blockIdx.y;
    int i = blockIdx.x * 256 + threadIdx.x;
    if (y < 3) {
        if (i >= 128 * 128) return;
        const float* src = (y == 0) ? Wq : (y == 1) ? Wk : Wv;
        u16* hi = (y == 0) ? WqTh : (y == 1) ? WkTh : WvTh;
        u16* lo = (y == 0) ? WqTl : (y == 1) ? WkTl : WvTl;
        int r = i >> 7, c = i & 127;
        float v = src[i];
        u16 h = f2bf(v);
        hi[c * 128 + r] = h;
        lo[c * 128 + r] = f2bf(v - bf2f(h));
    } else if (y == 3) {
        if (i >= 128 * 256) return;
        int r = i >> 8, c = i & 255;
        W1T[c * 128 + r] = f2bf(W1[i]);
    } else {
        if (i >= 256 * 128) return;
        int r = i >> 7, c = i & 127;
        W2T[c * 256 + r] = f2bf(W2[i]);
    }
}

// ---------------------------------------------------------------------------
// CSR build (once). srcbuf stores SOURCE node ids in CSR order.
// ---------------------------------------------------------------------------
__global__ __launch_bounds__(256) void zero_counts_kernel(int* cursor)
{
    int i = blockIdx.x * 256 + threadIdx.x;
    if (i < T_WIN * N_NODES) cursor[i] = 0;
}

__global__ __launch_bounds__(256) void hist_kernel(
    const int* __restrict__ ei, int* counts)
{
    int i = blockIdx.x * 256 + threadIdx.x;
    if (i >= T_WIN * E_PER_T) return;
    int ts = i / E_PER_T;
    int e  = i - ts * E_PER_T;
    int tar = ei[(ts * 2 + 1) * E_PER_T + e];
    atomicAdd(&counts[ts * N_NODES + tar], 1);
}

__global__ __launch_bounds__(1024) void scan_kernel(
    const int* __restrict__ counts, int* __restrict__ offs)
{
    __shared__ int buf[1024];
    __shared__ int carry;
    const int ts = blockIdx.x;
    const int tid = threadIdx.x;
    if (tid == 0) carry = 0;
    __syncthreads();
    for (int base = 0; base < N_NODES; base += 1024) {
        int i = base + tid;
        int v = (i < N_NODES) ? counts[ts * N_NODES + i] : 0;
        buf[tid] = v;
        __syncthreads();
        for (int o = 1; o < 1024; o <<= 1) {
            int t = (tid >= o) ? buf[tid - o] : 0;
            __syncthreads();
            buf[tid] += t;
            __syncthreads();
        }
        int incl = buf[tid];
        if (i < N_NODES) offs[ts * (N_NODES + 1) + i] = carry + incl - v;
        __syncthreads();
        if (tid == 1023) carry += incl;
        __syncthreads();
    }
    if (tid == 0) offs[ts * (N_NODES + 1) + N_NODES] = carry;
}

__global__ __launch_bounds__(256) void copy_cursor_kernel(
    const int* __restrict__ offs, int* cursor)
{
    int i = blockIdx.x * 256 + threadIdx.x;
    if (i >= T_WIN * N_NODES) return;
    int ts = i / N_NODES;
    int n  = i - ts * N_NODES;
    cursor[i] = offs[ts * (N_NODES + 1) + n];
}

__global__ __launch_bounds__(256) void fill_kernel(
    const int* __restrict__ ei, int* cursor, int* __restrict__ srcbuf)
{
    int i = blockIdx.x * 256 + threadIdx.x;
    if (i >= T_WIN * E_PER_T) return;
    int ts = i / E_PER_T;
    int e  = i - ts * E_PER_T;
    int src = ei[(ts * 2) * E_PER_T + e];
    int tar = ei[(ts * 2 + 1) * E_PER_T + e];
    int pos = atomicAdd(&cursor[ts * N_NODES + tar], 1);
    srcbuf[ts * E_PER_T + pos] = src;
}

// ---------------------------------------------------------------------------
// Split-bf16 MFMA projection, ALL 9 (mat x ts) in one dispatch.
// blockIdx.y: ts = y/3, mat = y%3 (0=Q,1=K,2=V).
// ---------------------------------------------------------------------------
__global__ __launch_bounds__(256) void project_all_kernel(
    const float* __restrict__ x,
    const u16* __restrict__ QTh, const u16* __restrict__ QTl, const float* __restrict__ bq,
    const u16* __restrict__ KTh, const u16* __restrict__ KTl, const float* __restrict__ bk,
    const u16* __restrict__ VTh, const u16* __restrict__ VTl, const float* __restrict__ bv,
    u16* __restrict__ Qall, u16* __restrict__ Kall, u16* __restrict__ Vall)
{
    const int p  = blockIdx.y;
    const int ts = p / 3, mat = p - ts * 3;
    const u16 *WTh, *WTl; const float* b; u16* O;
    if (mat == 0)      { WTh = QTh; WTl = QTl; b = bq; O = Qall; }
    else if (mat == 1) { WTh = KTh; WTl = KTl; b = bk; O = Kall; }
    else               { WTh = VTh; WTl = VTl; b = bv; O = Vall; }
    const size_t NHID = (size_t)N_NODES * HID;
    const float* __restrict__ xs = x + (size_t)ts * NHID;
    O += (size_t)ts * NHID;

    __shared__ u16 xhS[64 * 128];
    __shared__ u16 xlS[64 * 128];
    const int tid = threadIdx.x;
    const int n0 = blockIdx.x * 64;

    {   // stage: 4 threads/row, each covers 32 cols; hi/lo split, swizzled
        const int row = tid >> 2, q = tid & 3;
        const int n = n0 + row;
        const float4* xp = (const float4*)(xs + (size_t)n * 128 + q * 32);
        const int sbase = row * 128;
#pragma unroll
        for (int i = 0; i < 4; ++i) {
            float4 a = make_float4(0.f, 0.f, 0.f, 0.f), c = a;
            if (n < N_NODES) { a = xp[2 * i]; c = xp[2 * i + 1]; }
            float vv[8] = {a.x, a.y, a.z, a.w, c.x, c.y, c.z, c.w};
            uint4 uh, ul;
            unsigned* ph = (unsigned*)&uh;
            unsigned* pl = (unsigned*)&ul;
#pragma unroll
            for (int j = 0; j < 4; ++j) {
                u16 h0 = f2bf(vv[2 * j]), h1 = f2bf(vv[2 * j + 1]);
                ph[j] = (unsigned)h0 | ((unsigned)h1 << 16);
                u16 l0 = f2bf(vv[2 * j] - bf2f(h0));
                u16 l1 = f2bf(vv[2 * j + 1] - bf2f(h1));
                pl[j] = (unsigned)l0 | ((unsigned)l1 << 16);
            }
            int ch = (q * 4 + i) ^ (row & 15);
            *(uint4*)&xhS[sbase + ch * 8] = uh;
            *(uint4*)&xlS[sbase + ch * 8] = ul;
        }
    }
    __syncthreads();

    const int lane = tid & 63, w = tid >> 6;
    const int l15 = lane & 15, l4 = lane >> 4;
    f32x4 acc[4][2];
    const f32x4 z4 = {0.f, 0.f, 0.f, 0.f};
#pragma unroll
    for (int m = 0; m < 4; ++m)
#pragma unroll
        for (int n = 0; n < 2; ++n) acc[m][n] = z4;

#pragma unroll
    for (int ks = 0; ks < 4; ++ks) {
        const int ch = (ks * 4 + l4) ^ l15;
        bf16x8 ah[4], al[4];
#pragma unroll
        for (int m = 0; m < 4; ++m) {
            ah[m] = *(const bf16x8*)&xhS[(m * 16 + l15) * 128 + ch * 8];
            al[m] = *(const bf16x8*)&xlS[(m * 16 + l15) * 128 + ch * 8];
        }
        bf16x8 bh[2], bl[2];
#pragma unroll
        for (int n = 0; n < 2; ++n) {
            size_t wo = (size_t)(w * 32 + n * 16 + l15) * 128 + ks * 32 + l4 * 8;
            bh[n] = *(const bf16x8*)(WTh + wo);
            bl[n] = *(const bf16x8*)(WTl + wo);
        }
#pragma unroll
        for (int m = 0; m < 4; ++m)
#pragma unroll
            for (int n = 0; n < 2; ++n) {
                acc[m][n] = mfma16(ah[m], bh[n], acc[m][n]);
                acc[m][n] = mfma16(ah[m], bl[n], acc[m][n]);
                acc[m][n] = mfma16(al[m], bh[n], acc[m][n]);
            }
    }

    // C/D: col = lane&15, row = (lane>>4)*4 + reg
#pragma unroll
    for (int n = 0; n < 2; ++n) {
        int c = w * 32 + n * 16 + l15;
        float bb = b[c];
#pragma unroll
        for (int m = 0; m < 4; ++m)
#pragma unroll
            for (int j = 0; j < 4; ++j) {
                int r = m * 16 + l4 * 4 + j;
                int ng = n0 + r;
                if (ng < N_NODES)
                    O[(size_t)ng * 128 + c] = f2bf(acc[m][n][j] + bb);
            }
    }
}

// ---------------------------------------------------------------------------
// Fused attention, ALL t in one dispatch (blockIdx.y = t_tar).
// One wave per node. Phase A: logits (LDS cache: logit + gsrc=ts*N+src) +
// max/min; Phase B: exp sums; Phase C: flattened 4-way-prefetched V
// accumulate, single nt hat write. Slow path covers degree > CAP.
// ---------------------------------------------------------------------------
__global__ __launch_bounds__(256) void attn_fused_kernel(
    const u16* __restrict__ Qall, const u16* __restrict__ Kall,
    const u16* __restrict__ Vall,
    const int* __restrict__ offs, const int* __restrict__ srcbuf,
    float* __restrict__ hat_c_all, float* __restrict__ hat_s_all)
{
    __shared__ float logitS[4][CAP][NH];
    __shared__ int   srcS[4][CAP];
    const int t_tar = blockIdx.y;
    const int lane = threadIdx.x & 63;
    const int wave = threadIdx.x >> 6;
    const int node = blockIdx.x * 4 + wave;
    if (node >= N_NODES) return;

    const size_t NHID = (size_t)N_NODES * HID;
    float* __restrict__ hat_c = hat_c_all + (size_t)t_tar * NHID;
    float* __restrict__ hat_s = hat_s_all + (size_t)t_tar * NHID;
    const u16* __restrict__ Qt = Qall + (size_t)t_tar * NHID;
    const int h  = lane & 7;      // phase A/B: head
    const int j8 = lane >> 3;     // phase A/B: edge slot

    float (*lg)[NH] = logitS[wave];
    int* sx = srcS[wave];

    uint4 q0, q1;
    {
        const uint4* qp = (const uint4*)(Qt + (size_t)node * HID + h * DK);
        q0 = qp[0]; q1 = qp[1];
    }

    // ---- Phase A: logits + max/min + LDS cache (gsrc = ts*N + src) ----
    float mx = -1e30f, mn = 1e30f;
    int base = 0;
    for (int ts = 0; ts <= t_tar; ++ts) {
        const int beg = offs[ts * (N_NODES + 1) + node];
        const int end = offs[ts * (N_NODES + 1) + node + 1];
        const u16* __restrict__ K = Kall + (size_t)ts * NHID;
        const int* __restrict__ sb = srcbuf + (size_t)ts * E_PER_T;
        for (int j = beg + j8; j < end; j += 8) {
            int idx = base + (j - beg);
            int src = sb[j];
            const uint4* kp = (const uint4*)(K + (size_t)src * HID + h * DK);
            uint4 k0 = kp[0], k1 = kp[1];
            float s = 0.f;
            const unsigned* pa = (const unsigned*)&q0;
            const unsigned* pb = (const unsigned*)&k0;
#pragma unroll
            for (int i = 0; i < 4; ++i)
                s += __uint_as_float(pa[i] << 16) * __uint_as_float(pb[i] << 16)
                   + __uint_as_float(pa[i] & 0xffff0000u) * __uint_as_float(pb[i] & 0xffff0000u);
            pa = (const unsigned*)&q1; pb = (const unsigned*)&k1;
#pragma unroll
            for (int i = 0; i < 4; ++i)
                s += __uint_as_float(pa[i] << 16) * __uint_as_float(pb[i] << 16)
                   + __uint_as_float(pa[i] & 0xffff0000u) * __uint_as_float(pb[i] & 0xffff0000u);
            s *= 0.25f;  // / sqrt(16)
            mx = fmaxf(mx, s);
            mn = fminf(mn, s);
            if (idx < CAP) { lg[idx][h] = s; if (h == 0) sx[idx] = ts * N_NODES + src; }
        }
        base += end - beg;
    }
    const int dtot = base;
    if (dtot == 0) {
        size_t bidx = (size_t)node * HID + 2 * lane;
        f32x2 z2 = {0.f, 0.f};
        ntstore2(hat_c + bidx, z2);
        ntstore2(hat_s + bidx, z2);
        return;
    }
#pragma unroll
    for (int o = 8; o < 64; o <<= 1) {
        mx = fmaxf(mx, __shfl_xor(mx, o));
        mn = fminf(mn, __shfl_xor(mn, o));
    }

    // ---- Phase B: exp sums ----
    float sc = 0.f, ss = 0.f;
    {
        const int nfast = dtot < CAP ? dtot : CAP;
        for (int idx = j8; idx < nfast; idx += 8) {
            float a = lg[idx][h];
            sc += __expf(a - mx);
            ss += __expf(mn - a);
        }
        if (dtot > CAP) {
            int b2 = 0;
            for (int ts = 0; ts <= t_tar; ++ts) {
                const int beg = offs[ts * (N_NODES + 1) + node];
                const int end = offs[ts * (N_NODES + 1) + node + 1];
                const u16* K = Kall + (size_t)ts * NHID;
                const int* sb = srcbuf + (size_t)ts * E_PER_T;
                for (int j = beg + j8; j < end; j += 8) {
                    int idx = b2 + (j - beg);
                    if (idx >= CAP) {
                        int src = sb[j];
                        const uint4* kp = (const uint4*)(K + (size_t)src * HID + h * DK);
                        uint4 k0 = kp[0], k1 = kp[1];
                        float s = 0.f;
                        const unsigned* pa = (const unsigned*)&q0;
                        const unsigned* pb = (const unsigned*)&k0;
#pragma unroll
                        for (int i = 0; i < 4; ++i)
                            s += __uint_as_float(pa[i] << 16) * __uint_as_float(pb[i] << 16)
                               + __uint_as_float(pa[i] & 0xffff0000u) * __uint_as_float(pb[i] & 0xffff0000u);
                        pa = (const unsigned*)&q1; pb = (const unsigned*)&k1;
#pragma unroll
                        for (int i = 0; i < 4; ++i)
                            s += __uint_as_float(pa[i] << 16) * __uint_as_float(pb[i] << 16)
                               + __uint_as_float(pa[i] & 0xffff0000u) * __uint_as_float(pb[i] & 0xffff0000u);
                        s *= 0.25f;
                        sc += __expf(s - mx);
                        ss += __expf(mn - s);
                    }
                }
                b2 += end - beg;
            }
        }
    }
#pragma unroll
    for (int o = 8; o < 64; o <<= 1) {
        sc += __shfl_xor(sc, o);
        ss += __shfl_xor(ss, o);
    }

    // ---- Phase C: V accumulate (lane owns dims 2l,2l+1; head = lane>>3) ----
    const int h2 = lane >> 3;
    const float mc   = __shfl(mx, h2);
    const float mnn  = __shfl(mn, h2);
    const float isc  = 1.f / (__shfl(sc, h2) + 1e-16f);
    const float iss  = 1.f / (__shfl(ss, h2) + 1e-16f);

    float aC0 = 0.f, aC1 = 0.f, aS0 = 0.f, aS1 = 0.f;
    if (dtot <= CAP) {
        // fast: flattened LDS edge list, groups of 4 with prefetched loads
        const int dl = 2 * lane;
        for (int i0 = 0; i0 < dtot; i0 += 4) {
            int i1 = i0 + 1, i2 = i0 + 2, i3 = i0 + 3;
            int k1 = (i1 < dtot) ? i1 : i0;
            int k2 = (i2 < dtot) ? i2 : i0;
            int k3 = (i3 < dtot) ? i3 : i0;
            float a0 = lg[i0][h2], a1 = lg[k1][h2];
            float a2 = lg[k2][h2], a3 = lg[k3][h2];
            int g0 = sx[i0], g1 = sx[k1], g2 = sx[k2], g3 = sx[k3];
            unsigned w0 = *(const unsigned*)(Vall + (size_t)g0 * HID + dl);
            unsigned w1 = *(const unsigned*)(Vall + (size_t)g1 * HID + dl);
            unsigned w2 = *(const unsigned*)(Vall + (size_t)g2 * HID + dl);
            unsigned w3 = *(const unsigned*)(Vall + (size_t)g3 * HID + dl);
            float f1 = (i1 < dtot) ? 1.f : 0.f;
            float f2 = (i2 < dtot) ? 1.f : 0.f;
            float f3 = (i3 < dtot) ? 1.f : 0.f;
            {
                float pc = __expf(a0 - mc) * isc, ps = __expf(mnn - a0) * iss;
                float v0 = __uint_as_float(w0 << 16);
                float v1 = __uint_as_float(w0 & 0xffff0000u);
                aC0 += v0 * pc; aC1 += v1 * pc; aS0 += v0 * ps; aS1 += v1 * ps;
            }
            {
                float pc = __expf(a1 - mc) * isc * f1, ps = __expf(mnn - a1) * iss * f1;
                float v0 = __uint_as_float(w1 << 16);
                float v1 = __uint_as_float(w1 & 0xffff0000u);
                aC0 += v0 * pc; aC1 += v1 * pc; aS0 += v0 * ps; aS1 += v1 * ps;
            }
            {
                float pc = __expf(a2 - mc) * isc * f2, ps = __expf(mnn - a2) * iss * f2;
                float v0 = __uint_as_float(w2 << 16);
                float v1 = __uint_as_float(w2 & 0xffff0000u);
                aC0 += v0 * pc; aC1 += v1 * pc; aS0 += v0 * ps; aS1 += v1 * ps;
            }
            {
                float pc = __expf(a3 - mc) * isc * f3, ps = __expf(mnn - a3) * iss * f3;
                float v0 = __uint_as_float(w3 << 16);
                float v1 = __uint_as_float(w3 & 0xffff0000u);
                aC0 += v0 * pc; aC1 += v1 * pc; aS0 += v0 * ps; aS1 += v1 * ps;
            }
        }
    } else {
        // slow: original CSR walk (rare)
        int b2 = 0;
        for (int ts = 0; ts <= t_tar; ++ts) {
            const int beg = offs[ts * (N_NODES + 1) + node];
            const int end = offs[ts * (N_NODES + 1) + node + 1];
            const int* __restrict__ sb = srcbuf + (size_t)ts * E_PER_T;
            for (int j = beg; j < end; ++j) {
                int idx = b2 + (j - beg);
                float a; size_t gaddr;
                if (idx < CAP) {
                    a = lg[idx][h2];
                    gaddr = (size_t)sx[idx] * HID;
                } else {
                    int src = sb[j];
                    gaddr = ((size_t)ts * N_NODES + src) * HID;
                    unsigned qd = *(const unsigned*)(Qt + (size_t)node * HID + 2 * lane);
                    unsigned kd = *(const unsigned*)(Kall + gaddr + 2 * lane);
                    float p = __uint_as_float(qd << 16) * __uint_as_float(kd << 16)
                            + __uint_as_float(qd & 0xffff0000u) * __uint_as_float(kd & 0xffff0000u);
                    p += __shfl_xor(p, 1);
                    p += __shfl_xor(p, 2);
                    p += __shfl_xor(p, 4);
                    a = p * 0.25f;
                }
                float pc = __expf(a - mc) * isc;
                float ps = __expf(mnn - a) * iss;
                unsigned v2 = *(const unsigned*)(Vall + gaddr + 2 * lane);
                float v0 = __uint_as_float(v2 << 16);
                float v1 = __uint_as_float(v2 & 0xffff0000u);
                aC0 += v0 * pc; aC1 += v1 * pc;
                aS0 += v0 * ps; aS1 += v1 * ps;
            }
            b2 += end - beg;
        }
    }
    size_t bidx = (size_t)node * HID + 2 * lane;
    f32x2 rc = {aC0, aC1}, rs = {aS0, aS1};
    ntstore2(hat_c + bidx, rc);
    ntstore2(hat_s + bidx, rs);
}

// ---------------------------------------------------------------------------
// FFN via MFMA, ALL t (blockIdx.y = t), branches parallel across waves,
// 32-node tile. nt loads for hat/x (read-once), nt stores for out ->
// L2 stays reserved for the 128KB W1T/W2T working set.
// ---------------------------------------------------------------------------
__global__ __launch_bounds__(256, 4) void ffn_out_kernel(
    const float* __restrict__ hat_c_all, const float* __restrict__ hat_s_all,
    const float* __restrict__ x,
    const float* __restrict__ ln_s, const float* __restrict__ ln_b,
    const u16* __restrict__ W1T, const float* __restrict__ b1,
    const u16* __restrict__ W2T, const float* __restrict__ b2,
    float* __restrict__ out)
{
    __shared__ char ldsbuf[32768];
    u16* hnS = (u16*)ldsbuf;                 // [2][32*128] bf16 (16 KB)
    u16* chS = (u16*)(ldsbuf + 16384);       // [2][2][32*64] bf16 (16 KB)
    float* rS = (float*)ldsbuf;              // [2][32][128] f32 overlay (32 KB)

    const int t_tar = blockIdx.y;
    const int n0 = blockIdx.x * 32;
    const int tid = threadIdx.x;
    const size_t NHID = (size_t)N_NODES * HID;
    const float* __restrict__ hat_c = hat_c_all + (size_t)t_tar * NHID;
    const float* __restrict__ hat_s = hat_s_all + (size_t)t_tar * NHID;
    const float* __restrict__ xt = x + (size_t)t_tar * NHID;
    const size_t TS = (size_t)T_WIN * N_NODES * HID;
    const size_t outbase = (size_t)t_tar * NHID;

    const int lane = tid & 63;
    const int wave = tid >> 6;
    const int br   = wave >> 1;          // GEMM branch: 0 causal, 1 spurious
    const int wv   = wave & 1;           // wave-within-branch
    const int l15 = lane & 15, l4 = lane >> 4;
    const f32x4 z4 = {0.f, 0.f, 0.f, 0.f};

    // LN mapping: brL = tid>>7 (== br), 4 threads/row, 32 cols each
    const int brL = tid >> 7;
    const int rowL = (tid & 127) >> 2, qL = tid & 3;
    const int nL = n0 + rowL;
    const float* __restrict__ hatL = brL ? hat_s : hat_c;

    float v[32];   // pre-LN row segment (hat [+x]) -- LIVE through GEMMs

    // ---- LayerNorm (nt loads: hat/x are read exactly once) ----
    {
        float s = 0.f, s2 = 0.f;
        if (nL < N_NODES) {
            const float* hp = hatL + (size_t)nL * 128 + qL * 32;
            const float* xp = xt + (size_t)nL * 128 + qL * 32;
#pragma unroll
            for (int i = 0; i < 8; ++i) {
                f32x4 a = ntload4(hp + 4 * i);
                if (brL == 0) {
                    f32x4 bx = ntload4(xp + 4 * i);
                    a += bx;
                }
                v[4 * i] = a.x; v[4 * i + 1] = a.y;
                v[4 * i + 2] = a.z; v[4 * i + 3] = a.w;
                s  += a.x + a.y + a.z + a.w;
                s2 += a.x * a.x + a.y * a.y + a.z * a.z + a.w * a.w;
            }
        } else {
#pragma unroll
            for (int i = 0; i < 32; ++i) v[i] = 0.f;
        }
        s  += __shfl_xor(s, 1);  s  += __shfl_xor(s, 2);
        s2 += __shfl_xor(s2, 1); s2 += __shfl_xor(s2, 2);
        float mu  = s * (1.f / 128.f);
        float var = s2 * (1.f / 128.f) - mu * mu;
        float rstd = rsqrtf(var + 1e-5f);
        const int sbase = brL * 4096 + rowL * 128;
#pragma unroll
        for (int i = 0; i < 4; ++i) {
            uint4 uh; unsigned* ph = (unsigned*)&uh;
#pragma unroll
            for (int j = 0; j < 4; ++j) {
                int c0 = qL * 32 + i * 8 + 2 * j;
                float h0 = (v[i * 8 + 2 * j]     - mu) * rstd * ln_s[c0]     + ln_b[c0];
                float h1 = (v[i * 8 + 2 * j + 1] - mu) * rstd * ln_s[c0 + 1] + ln_b[c0 + 1];
                if (nL >= N_NODES) { h0 = 0.f; h1 = 0.f; }
                ph[j] = (unsigned)f2bf(h0) | ((unsigned)f2bf(h1) << 16);
            }
            int ch = (qL * 4 + i) ^ (rowL & 15);
            *(uint4*)&hnS[sbase + ch * 8] = uh;
        }
    }
    __syncthreads();

    // ---- chunked GEMM1 -> GELU -> GEMM2 (K-fused, dbuf chS) ----
    f32x4 a2[2][4];
#pragma unroll
    for (int m = 0; m < 2; ++m)
#pragma unroll
        for (int n = 0; n < 4; ++n) a2[m][n] = z4;

#pragma unroll
    for (int cc = 0; cc < 4; ++cc) {
        f32x4 a1[2][2];
#pragma unroll
        for (int m = 0; m < 2; ++m)
#pragma unroll
            for (int n = 0; n < 2; ++n) a1[m][n] = z4;
#pragma unroll
        for (int ks = 0; ks < 4; ++ks) {
            const int ch = (ks * 4 + l4) ^ l15;
            bf16x8 af[2];
#pragma unroll
            for (int m = 0; m < 2; ++m)
                af[m] = *(const bf16x8*)&hnS[br * 4096 + (m * 16 + l15) * 128 + ch * 8];
#pragma unroll
            for (int n = 0; n < 2; ++n) {
                bf16x8 bfr = *(const bf16x8*)(W1T
                    + (size_t)(cc * 64 + wv * 32 + n * 16 + l15) * 128 + ks * 32 + l4 * 8);
#pragma unroll
                for (int m = 0; m < 2; ++m)
                    a1[m][n] = mfma16(af[m], bfr, a1[m][n]);
            }
        }
        // bias + exact GELU -> swizzled bf16 chunk tile
        u16* chw = chS + ((cc & 1) * 2 + br) * (32 * 64);
#pragma unroll
        for (int n = 0; n < 2; ++n) {
            int cl = wv * 32 + n * 16 + l15;        // local col 0..63
            float bb = b1[cc * 64 + cl];
#pragma unroll
            for (int m = 0; m < 2; ++m)
#pragma unroll
                for (int j = 0; j < 4; ++j) {
                    int r = m * 16 + l4 * 4 + j;
                    float zz = a1[m][n][j] + bb;
                    float g = 0.5f * zz * (1.f + erff(zz * 0.70710678118654752f));
                    chw[r * 64 + (((cl >> 3) ^ (r & 7)) * 8) + (cl & 7)] = f2bf(g);
                }
        }
        __syncthreads();
        // GEMM2 partial: K-slice cc*64..cc*64+63
        const u16* chr = chS + ((cc & 1) * 2 + br) * (32 * 64);
#pragma unroll
        for (int ks2 = 0; ks2 < 2; ++ks2) {
            const int ch8 = (ks2 * 4 + l4) ^ (l15 & 7);
            bf16x8 af[2];
#pragma unroll
            for (int m = 0; m < 2; ++m)
                af[m] = *(const bf16x8*)&chr[(m * 16 + l15) * 64 + ch8 * 8];
#pragma unroll
            for (int n = 0; n < 4; ++n) {
                bf16x8 bfr = *(const bf16x8*)(W2T
                    + (size_t)(wv * 64 + n * 16 + l15) * 256 + cc * 64 + ks2 * 32 + l4 * 8);
#pragma unroll
                for (int m = 0; m < 2; ++m)
                    a2[m][n] = mfma16(af[m], bfr, a2[m][n]);
            }
        }
    }
    __syncthreads();   // hnS + chS now dead -> rS overlay is safe

    // ---- r = a2 + b2 -> LDS (XOR-swizzled fp32) ----
#pragma unroll
    for (int n = 0; n < 4; ++n) {
        int c = wv * 64 + n * 16 + l15;
        float bb = b2[c];
#pragma unroll
        for (int m = 0; m < 2; ++m)
#pragma unroll
            for (int j = 0; j < 4; ++j) {
                int r = m * 16 + l4 * 4 + j;
                rS[br * 4096 + r * 128 + (c ^ ((r & 7) << 2))] = a2[m][n][j] + bb;
            }
    }
    __syncthreads();

    // ---- LN threads: fold val = v + r into rS in place ----
    {
        const int swzL = (rowL & 7) << 2;
#pragma unroll
        for (int i = 0; i < 8; ++i) {
            int coff = brL * 4096 + rowL * 128 + ((qL * 32 + i * 4) ^ swzL);
            float4 rv = *(const float4*)&rS[coff];
            rv.x += v[4 * i];     rv.y += v[4 * i + 1];
            rv.z += v[4 * i + 2]; rv.w += v[4 * i + 3];
            *(float4*)&rS[coff] = rv;
        }
    }
    __syncthreads();

    // ---- streaming nt stores: fully contiguous (1KB/wave/instr) ----
    {
        const int nrows = N_NODES - n0;   // valid rows in tile (<=32 means tail)
        float* o0 = out + outbase + (size_t)n0 * 128;
        float* o1 = out + TS + outbase + (size_t)n0 * 128;
        float* o2 = out + 2 * TS + outbase + (size_t)n0 * 128;
#pragma unroll
        for (int it = 0; it < 4; ++it) {
            int lin = it * 1024 + tid * 4;
            int row = lin >> 7, col = lin & 127;
            int sw  = col ^ ((row & 7) << 2);
            if (row < nrows) {
                f32x4 cv = *(const f32x4*)&rS[row * 128 + sw];
                f32x4 sv = *(const f32x4*)&rS[4096 + row * 128 + sw];
                ntstore4(&o1[lin], cv);
                ntstore4(&o2[lin], sv);
                ntstore4(&o0[lin], cv + sv);
            }
        }
    }
}

extern "C" void kernel_launch(void* const* d_in, const int* in_sizes, int n_in,
                              void* d_out, int out_size, void* d_ws, size_t ws_size,
                              hipStream_t stream) {
    const float* x    = (const float*)d_in[0];
    const int*   ei   = (const int*)  d_in[1];
    const float* Wq   = (const float*)d_in[2];
    const float* bq   = (const float*)d_in[3];
    const float* Wk   = (const float*)d_in[4];
    const float* bk   = (const float*)d_in[5];
    const float* Wv   = (const float*)d_in[6];
    const float* bv   = (const float*)d_in[7];
    const float* ln_s = (const float*)d_in[8];
    const float* ln_b = (const float*)d_in[9];
    const float* W1   = (const float*)d_in[10];
    const float* b1   = (const float*)d_in[11];
    const float* W2   = (const float*)d_in[12];
    const float* b2   = (const float*)d_in[13];
    float* out = (float*)d_out;

    // ---- Workspace layout (~274 MB) ----
    const size_t NHID = (size_t)N_NODES * HID;  // 6,400,000
    char* p = (char*)d_ws;
    auto alloc = [&p](size_t bytes) -> void* {
        void* r = (void*)p;
        p += (bytes + 255) & ~(size_t)255;
        return r;
    };
    float* hat_c = (float*)alloc(3 * NHID * 4);   // [t][N][HID]
    float* hat_s = (float*)alloc(3 * NHID * 4);
    int* offs    = (int*)alloc((size_t)T_WIN * (N_NODES + 1) * 4);
    int* cursor  = (int*)alloc((size_t)T_WIN * N_NODES * 4);
    int* srcbuf  = (int*)alloc((size_t)T_WIN * E_PER_T * 4);
    u16* WqTh = (u16*)alloc(128 * 128 * 2);
    u16* WqTl = (u16*)alloc(128 * 128 * 2);
    u16* WkTh = (u16*)alloc(128 * 128 * 2);
    u16* WkTl = (u16*)alloc(128 * 128 * 2);
    u16* WvTh = (u16*)alloc(128 * 128 * 2);
    u16* WvTl = (u16*)alloc(128 * 128 * 2);
    u16* W1T  = (u16*)alloc(128 * 256 * 2);
    u16* W2T  = (u16*)alloc(256 * 128 * 2);
    u16* Qall = (u16*)alloc(3 * NHID * 2);
    u16* Kall = (u16*)alloc(3 * NHID * 2);
    u16* Vall = (u16*)alloc(3 * NHID * 2);

    const int PROJ_BLOCKS = (N_NODES + 63) / 64;          // 782
    const int FFN_BLOCKS  = (N_NODES + 31) / 32;          // 1563
    const int NODE_BLOCKS = (N_NODES + 3) / 4;            // 12500
    const int TN_BLOCKS   = (T_WIN * N_NODES + 255) / 256;
    const int TE_BLOCKS   = (T_WIN * E_PER_T + 255) / 256;

    // ---- weight prep (one dispatch) ----
    {
        dim3 wg(128, 5);
        wprep_kernel<<<wg, 256, 0, stream>>>(
            Wq, Wk, Wv, W1, W2,
            WqTh, WqTl, WkTh, WkTl, WvTh, WvTl, W1T, W2T);
    }

    // ---- CSR build ----
    zero_counts_kernel<<<TN_BLOCKS, 256, 0, stream>>>(cursor);
    hist_kernel<<<TE_BLOCKS, 256, 0, stream>>>(ei, cursor);
    scan_kernel<<<T_WIN, 1024, 0, stream>>>(cursor, offs);
    copy_cursor_kernel<<<TN_BLOCKS, 256, 0, stream>>>(offs, cursor);
    fill_kernel<<<TE_BLOCKS, 256, 0, stream>>>(ei, cursor, srcbuf);

    // ---- all projections (Q/K/V x 3 ts) in one dispatch ----
    {
        dim3 pg(PROJ_BLOCKS, 9);
        project_all_kernel<<<pg, 256, 0, stream>>>(
            x, WqTh, WqTl, bq, WkTh, WkTl, bk, WvTh, WvTl, bv,
            Qall, Kall, Vall);
    }

    // ---- attention, all t in one dispatch ----
    {
        dim3 ag(NODE_BLOCKS, T_WIN);
        attn_fused_kernel<<<ag, 256, 0, stream>>>(
            Qall, Kall, Vall, offs, srcbuf, hat_c, hat_s);
    }

    // ---- FFN + output, all t in one dispatch ----
    {
        dim3 fg(FFN_BLOCKS, T_WIN);
        ffn_out_kernel<<<fg, 256, 0, stream>>>(
            hat_c, hat_s, x, ln_s, ln_b, W1T, b1, W2T, b2, out);
    }
}

// Round 8
// 1026.683 us; speedup vs baseline: 1.0551x; 1.0551x over previous
//
#include <hip/hip_runtime.h>
#include <math.h>

// Problem constants (from reference)
#define T_WIN   3
#define N_NODES 50000
#define HID     128
#define E_PER_T 100000
#define NH      8
#define DK      16
#define CAP     64   // per-node LDS logit cache (avg total degree ~6; slow path covers overflow)

// R12: R11's nt LOADS were the regression (FETCH 522->770MB: L2-bypass loses
// line reuse). Revert nt loads + attn nt hat stores (hat has cross-dispatch
// reuse -> keep L2/L3-resident); KEEP nt stores on out (write-side win).
// New: hat stored as bf16 (halves attn write + ffn hat read; error ~0.004
// vs existing 0.04-0.09 absmax). ffn launch_bounds -> 5 blocks/CU.

typedef unsigned short u16;
typedef __attribute__((ext_vector_type(8))) short bf16x8;   // 8 bf16 = 4 VGPR
typedef __attribute__((ext_vector_type(4))) float f32x4;
typedef __attribute__((ext_vector_type(2))) float f32x2;

__device__ __forceinline__ u16 f2bf(float v) {              // RNE f32->bf16
    unsigned u = __float_as_uint(v);
    return (u16)((u + 0x7fffu + ((u >> 16) & 1u)) >> 16);
}
__device__ __forceinline__ float bf2f(u16 u) {
    return __uint_as_float(((unsigned)u) << 16);
}
__device__ __forceinline__ f32x4 mfma16(bf16x8 a, bf16x8 b, f32x4 c) {
    return __builtin_amdgcn_mfma_f32_16x16x32_bf16(a, b, c, 0, 0, 0);
}
__device__ __forceinline__ void ntstore4(float* p, f32x4 v) {
    __builtin_nontemporal_store(v, (f32x4*)p);
}

// ---------------------------------------------------------------------------
// Weight prep, ONE dispatch. y=0..2: hi/lo split of Wq/Wk/Wv (128x128);
// y=3: W1 (128x256) bf16; y=4: W2 (256x128) bf16. dst layout [C][R].
// ---------------------------------------------------------------------------
__global__ __launch_bounds__(256) void wprep_kernel(
    const float* __restrict__ Wq, const float* __restrict__ Wk,
    const float* __restrict__ Wv, const float* __restrict__ W1,
    const float* __restrict__ W2,
    u16* __restrict__ WqTh, u16* __restrict__ WqTl,
    u16* __restrict__ WkTh, u16* __restrict__ WkTl,
    u16* __restrict__ WvTh, u16* __restrict__ WvTl,
    u16* __restrict__ W1T, u16* __restrict__ W2T)
{
    const int y = blockIdx.y;
    int i = blockIdx.x * 256 + threadIdx.x;
    if (y < 3) {
        if (i >= 128 * 128) return;
        const float* src = (y == 0) ? Wq : (y == 1) ? Wk : Wv;
        u16* hi = (y == 0) ? WqTh : (y == 1) ? WkTh : WvTh;
        u16* lo = (y == 0) ? WqTl : (y == 1) ? WkTl : WvTl;
        int r = i >> 7, c = i & 127;
        float v = src[i];
        u16 h = f2bf(v);
        hi[c * 128 + r] = h;
        lo[c * 128 + r] = f2bf(v - bf2f(h));
    } else if (y == 3) {
        if (i >= 128 * 256) return;
        int r = i >> 8, c = i & 255;
        W1T[c * 128 + r] = f2bf(W1[i]);
    } else {
        if (i >= 256 * 128) return;
        int r = i >> 7, c = i & 127;
        W2T[c * 256 + r] = f2bf(W2[i]);
    }
}

// ---------------------------------------------------------------------------
// CSR build (once). srcbuf stores SOURCE node ids in CSR order.
// ---------------------------------------------------------------------------
__global__ __launch_bounds__(256) void zero_counts_kernel(int* cursor)
{
    int i = blockIdx.x * 256 + threadIdx.x;
    if (i < T_WIN * N_NODES) cursor[i] = 0;
}

__global__ __launch_bounds__(256) void hist_kernel(
    const int* __restrict__ ei, int* counts)
{
    int i = blockIdx.x * 256 + threadIdx.x;
    if (i >= T_WIN * E_PER_T) return;
    int ts = i / E_PER_T;
    int e  = i - ts * E_PER_T;
    int tar = ei[(ts * 2 + 1) * E_PER_T + e];
    atomicAdd(&counts[ts * N_NODES + tar], 1);
}

__global__ __launch_bounds__(1024) void scan_kernel(
    const int* __restrict__ counts, int* __restrict__ offs)
{
    __shared__ int buf[1024];
    __shared__ int carry;
    const int ts = blockIdx.x;
    const int tid = threadIdx.x;
    if (tid == 0) carry = 0;
    __syncthreads();
    for (int base = 0; base < N_NODES; base += 1024) {
        int i = base + tid;
        int v = (i < N_NODES) ? counts[ts * N_NODES + i] : 0;
        buf[tid] = v;
        __syncthreads();
        for (int o = 1; o < 1024; o <<= 1) {
            int t = (tid >= o) ? buf[tid - o] : 0;
            __syncthreads();
            buf[tid] += t;
            __syncthreads();
        }
        int incl = buf[tid];
        if (i < N_NODES) offs[ts * (N_NODES + 1) + i] = carry + incl - v;
        __syncthreads();
        if (tid == 1023) carry += incl;
        __syncthreads();
    }
    if (tid == 0) offs[ts * (N_NODES + 1) + N_NODES] = carry;
}

__global__ __launch_bounds__(256) void copy_cursor_kernel(
    const int* __restrict__ offs, int* cursor)
{
    int i = blockIdx.x * 256 + threadIdx.x;
    if (i >= T_WIN * N_NODES) return;
    int ts = i / N_NODES;
    int n  = i - ts * N_NODES;
    cursor[i] = offs[ts * (N_NODES + 1) + n];
}

__global__ __launch_bounds__(256) void fill_kernel(
    const int* __restrict__ ei, int* cursor, int* __restrict__ srcbuf)
{
    int i = blockIdx.x * 256 + threadIdx.x;
    if (i >= T_WIN * E_PER_T) return;
    int ts = i / E_PER_T;
    int e  = i - ts * E_PER_T;
    int src = ei[(ts * 2) * E_PER_T + e];
    int tar = ei[(ts * 2 + 1) * E_PER_T + e];
    int pos = atomicAdd(&cursor[ts * N_NODES + tar], 1);
    srcbuf[ts * E_PER_T + pos] = src;
}

// ---------------------------------------------------------------------------
// Split-bf16 MFMA projection, ALL 9 (mat x ts) in one dispatch.
// blockIdx.y: ts = y/3, mat = y%3 (0=Q,1=K,2=V).
// ---------------------------------------------------------------------------
__global__ __launch_bounds__(256) void project_all_kernel(
    const float* __restrict__ x,
    const u16* __restrict__ QTh, const u16* __restrict__ QTl, const float* __restrict__ bq,
    const u16* __restrict__ KTh, const u16* __restrict__ KTl, const float* __restrict__ bk,
    const u16* __restrict__ VTh, const u16* __restrict__ VTl, const float* __restrict__ bv,
    u16* __restrict__ Qall, u16* __restrict__ Kall, u16* __restrict__ Vall)
{
    const int p  = blockIdx.y;
    const int ts = p / 3, mat = p - ts * 3;
    const u16 *WTh, *WTl; const float* b; u16* O;
    if (mat == 0)      { WTh = QTh; WTl = QTl; b = bq; O = Qall; }
    else if (mat == 1) { WTh = KTh; WTl = KTl; b = bk; O = Kall; }
    else               { WTh = VTh; WTl = VTl; b = bv; O = Vall; }
    const size_t NHID = (size_t)N_NODES * HID;
    const float* __restrict__ xs = x + (size_t)ts * NHID;
    O += (size_t)ts * NHID;

    __shared__ u16 xhS[64 * 128];
    __shared__ u16 xlS[64 * 128];
    const int tid = threadIdx.x;
    const int n0 = blockIdx.x * 64;

    {   // stage: 4 threads/row, each covers 32 cols; hi/lo split, swizzled
        const int row = tid >> 2, q = tid & 3;
        const int n = n0 + row;
        const float4* xp = (const float4*)(xs + (size_t)n * 128 + q * 32);
        const int sbase = row * 128;
#pragma unroll
        for (int i = 0; i < 4; ++i) {
            float4 a = make_float4(0.f, 0.f, 0.f, 0.f), c = a;
            if (n < N_NODES) { a = xp[2 * i]; c = xp[2 * i + 1]; }
            float vv[8] = {a.x, a.y, a.z, a.w, c.x, c.y, c.z, c.w};
            uint4 uh, ul;
            unsigned* ph = (unsigned*)&uh;
            unsigned* pl = (unsigned*)&ul;
#pragma unroll
            for (int j = 0; j < 4; ++j) {
                u16 h0 = f2bf(vv[2 * j]), h1 = f2bf(vv[2 * j + 1]);
                ph[j] = (unsigned)h0 | ((unsigned)h1 << 16);
                u16 l0 = f2bf(vv[2 * j] - bf2f(h0));
                u16 l1 = f2bf(vv[2 * j + 1] - bf2f(h1));
                pl[j] = (unsigned)l0 | ((unsigned)l1 << 16);
            }
            int ch = (q * 4 + i) ^ (row & 15);
            *(uint4*)&xhS[sbase + ch * 8] = uh;
            *(uint4*)&xlS[sbase + ch * 8] = ul;
        }
    }
    __syncthreads();

    const int lane = tid & 63, w = tid >> 6;
    const int l15 = lane & 15, l4 = lane >> 4;
    f32x4 acc[4][2];
    const f32x4 z4 = {0.f, 0.f, 0.f, 0.f};
#pragma unroll
    for (int m = 0; m < 4; ++m)
#pragma unroll
        for (int n = 0; n < 2; ++n) acc[m][n] = z4;

#pragma unroll
    for (int ks = 0; ks < 4; ++ks) {
        const int ch = (ks * 4 + l4) ^ l15;
        bf16x8 ah[4], al[4];
#pragma unroll
        for (int m = 0; m < 4; ++m) {
            ah[m] = *(const bf16x8*)&xhS[(m * 16 + l15) * 128 + ch * 8];
            al[m] = *(const bf16x8*)&xlS[(m * 16 + l15) * 128 + ch * 8];
        }
        bf16x8 bh[2], bl[2];
#pragma unroll
        for (int n = 0; n < 2; ++n) {
            size_t wo = (size_t)(w * 32 + n * 16 + l15) * 128 + ks * 32 + l4 * 8;
            bh[n] = *(const bf16x8*)(WTh + wo);
            bl[n] = *(const bf16x8*)(WTl + wo);
        }
#pragma unroll
        for (int m = 0; m < 4; ++m)
#pragma unroll
            for (int n = 0; n < 2; ++n) {
                acc[m][n] = mfma16(ah[m], bh[n], acc[m][n]);
                acc[m][n] = mfma16(ah[m], bl[n], acc[m][n]);
                acc[m][n] = mfma16(al[m], bh[n], acc[m][n]);
            }
    }

    // C/D: col = lane&15, row = (lane>>4)*4 + reg
#pragma unroll
    for (int n = 0; n < 2; ++n) {
        int c = w * 32 + n * 16 + l15;
        float bb = b[c];
#pragma unroll
        for (int m = 0; m < 4; ++m)
#pragma unroll
            for (int j = 0; j < 4; ++j) {
                int r = m * 16 + l4 * 4 + j;
                int ng = n0 + r;
                if (ng < N_NODES)
                    O[(size_t)ng * 128 + c] = f2bf(acc[m][n][j] + bb);
            }
    }
}

// ---------------------------------------------------------------------------
// Fused attention, ALL t in one dispatch (blockIdx.y = t_tar).
// One wave per node. Phase A: logits (LDS cache: logit + gsrc=ts*N+src) +
// max/min; Phase B: exp sums; Phase C: flattened 4-way-prefetched V
// accumulate. hat written as bf16 (normal stores: L2/L3-resident for ffn).
// ---------------------------------------------------------------------------
__global__ __launch_bounds__(256) void attn_fused_kernel(
    const u16* __restrict__ Qall, const u16* __restrict__ Kall,
    const u16* __restrict__ Vall,
    const int* __restrict__ offs, const int* __restrict__ srcbuf,
    u16* __restrict__ hat_c_all, u16* __restrict__ hat_s_all)
{
    __shared__ float logitS[4][CAP][NH];
    __shared__ int   srcS[4][CAP];
    const int t_tar = blockIdx.y;
    const int lane = threadIdx.x & 63;
    const int wave = threadIdx.x >> 6;
    const int node = blockIdx.x * 4 + wave;
    if (node >= N_NODES) return;

    const size_t NHID = (size_t)N_NODES * HID;
    u16* __restrict__ hat_c = hat_c_all + (size_t)t_tar * NHID;
    u16* __restrict__ hat_s = hat_s_all + (size_t)t_tar * NHID;
    const u16* __restrict__ Qt = Qall + (size_t)t_tar * NHID;
    const int h  = lane & 7;      // phase A/B: head
    const int j8 = lane >> 3;     // phase A/B: edge slot

    float (*lg)[NH] = logitS[wave];
    int* sx = srcS[wave];

    uint4 q0, q1;
    {
        const uint4* qp = (const uint4*)(Qt + (size_t)node * HID + h * DK);
        q0 = qp[0]; q1 = qp[1];
    }

    // ---- Phase A: logits + max/min + LDS cache (gsrc = ts*N + src) ----
    float mx = -1e30f, mn = 1e30f;
    int base = 0;
    for (int ts = 0; ts <= t_tar; ++ts) {
        const int beg = offs[ts * (N_NODES + 1) + node];
        const int end = offs[ts * (N_NODES + 1) + node + 1];
        const u16* __restrict__ K = Kall + (size_t)ts * NHID;
        const int* __restrict__ sb = srcbuf + (size_t)ts * E_PER_T;
        for (int j = beg + j8; j < end; j += 8) {
            int idx = base + (j - beg);
            int src = sb[j];
            const uint4* kp = (const uint4*)(K + (size_t)src * HID + h * DK);
            uint4 k0 = kp[0], k1 = kp[1];
            float s = 0.f;
            const unsigned* pa = (const unsigned*)&q0;
            const unsigned* pb = (const unsigned*)&k0;
#pragma unroll
            for (int i = 0; i < 4; ++i)
                s += __uint_as_float(pa[i] << 16) * __uint_as_float(pb[i] << 16)
                   + __uint_as_float(pa[i] & 0xffff0000u) * __uint_as_float(pb[i] & 0xffff0000u);
            pa = (const unsigned*)&q1; pb = (const unsigned*)&k1;
#pragma unroll
            for (int i = 0; i < 4; ++i)
                s += __uint_as_float(pa[i] << 16) * __uint_as_float(pb[i] << 16)
                   + __uint_as_float(pa[i] & 0xffff0000u) * __uint_as_float(pb[i] & 0xffff0000u);
            s *= 0.25f;  // / sqrt(16)
            mx = fmaxf(mx, s);
            mn = fminf(mn, s);
            if (idx < CAP) { lg[idx][h] = s; if (h == 0) sx[idx] = ts * N_NODES + src; }
        }
        base += end - beg;
    }
    const int dtot = base;
    if (dtot == 0) {
        size_t bidx = (size_t)node * HID + 2 * lane;
        *(unsigned*)(hat_c + bidx) = 0u;
        *(unsigned*)(hat_s + bidx) = 0u;
        return;
    }
#pragma unroll
    for (int o = 8; o < 64; o <<= 1) {
        mx = fmaxf(mx, __shfl_xor(mx, o));
        mn = fminf(mn, __shfl_xor(mn, o));
    }

    // ---- Phase B: exp sums ----
    float sc = 0.f, ss = 0.f;
    {
        const int nfast = dtot < CAP ? dtot : CAP;
        for (int idx = j8; idx < nfast; idx += 8) {
            float a = lg[idx][h];
            sc += __expf(a - mx);
            ss += __expf(mn - a);
        }
        if (dtot > CAP) {
            int b2 = 0;
            for (int ts = 0; ts <= t_tar; ++ts) {
                const int beg = offs[ts * (N_NODES + 1) + node];
                const int end = offs[ts * (N_NODES + 1) + node + 1];
                const u16* K = Kall + (size_t)ts * NHID;
                const int* sb = srcbuf + (size_t)ts * E_PER_T;
                for (int j = beg + j8; j < end; j += 8) {
                    int idx = b2 + (j - beg);
                    if (idx >= CAP) {
                        int src = sb[j];
                        const uint4* kp = (const uint4*)(K + (size_t)src * HID + h * DK);
                        uint4 k0 = kp[0], k1 = kp[1];
                        float s = 0.f;
                        const unsigned* pa = (const unsigned*)&q0;
                        const unsigned* pb = (const unsigned*)&k0;
#pragma unroll
                        for (int i = 0; i < 4; ++i)
                            s += __uint_as_float(pa[i] << 16) * __uint_as_float(pb[i] << 16)
                               + __uint_as_float(pa[i] & 0xffff0000u) * __uint_as_float(pb[i] & 0xffff0000u);
                        pa = (const unsigned*)&q1; pb = (const unsigned*)&k1;
#pragma unroll
                        for (int i = 0; i < 4; ++i)
                            s += __uint_as_float(pa[i] << 16) * __uint_as_float(pb[i] << 16)
                               + __uint_as_float(pa[i] & 0xffff0000u) * __uint_as_float(pb[i] & 0xffff0000u);
                        s *= 0.25f;
                        sc += __expf(s - mx);
                        ss += __expf(mn - s);
                    }
                }
                b2 += end - beg;
            }
        }
    }
#pragma unroll
    for (int o = 8; o < 64; o <<= 1) {
        sc += __shfl_xor(sc, o);
        ss += __shfl_xor(ss, o);
    }

    // ---- Phase C: V accumulate (lane owns dims 2l,2l+1; head = lane>>3) ----
    const int h2 = lane >> 3;
    const float mc   = __shfl(mx, h2);
    const float mnn  = __shfl(mn, h2);
    const float isc  = 1.f / (__shfl(sc, h2) + 1e-16f);
    const float iss  = 1.f / (__shfl(ss, h2) + 1e-16f);

    float aC0 = 0.f, aC1 = 0.f, aS0 = 0.f, aS1 = 0.f;
    if (dtot <= CAP) {
        // fast: flattened LDS edge list, groups of 4 with prefetched loads
        const int dl = 2 * lane;
        for (int i0 = 0; i0 < dtot; i0 += 4) {
            int i1 = i0 + 1, i2 = i0 + 2, i3 = i0 + 3;
            int k1 = (i1 < dtot) ? i1 : i0;
            int k2 = (i2 < dtot) ? i2 : i0;
            int k3 = (i3 < dtot) ? i3 : i0;
            float a0 = lg[i0][h2], a1 = lg[k1][h2];
            float a2 = lg[k2][h2], a3 = lg[k3][h2];
            int g0 = sx[i0], g1 = sx[k1], g2 = sx[k2], g3 = sx[k3];
            unsigned w0 = *(const unsigned*)(Vall + (size_t)g0 * HID + dl);
            unsigned w1 = *(const unsigned*)(Vall + (size_t)g1 * HID + dl);
            unsigned w2 = *(const unsigned*)(Vall + (size_t)g2 * HID + dl);
            unsigned w3 = *(const unsigned*)(Vall + (size_t)g3 * HID + dl);
            float f1 = (i1 < dtot) ? 1.f : 0.f;
            float f2 = (i2 < dtot) ? 1.f : 0.f;
            float f3 = (i3 < dtot) ? 1.f : 0.f;
            {
                float pc = __expf(a0 - mc) * isc, ps = __expf(mnn - a0) * iss;
                float v0 = __uint_as_float(w0 << 16);
                float v1 = __uint_as_float(w0 & 0xffff0000u);
                aC0 += v0 * pc; aC1 += v1 * pc; aS0 += v0 * ps; aS1 += v1 * ps;
            }
            {
                float pc = __expf(a1 - mc) * isc * f1, ps = __expf(mnn - a1) * iss * f1;
                float v0 = __uint_as_float(w1 << 16);
                float v1 = __uint_as_float(w1 & 0xffff0000u);
                aC0 += v0 * pc; aC1 += v1 * pc; aS0 += v0 * ps; aS1 += v1 * ps;
            }
            {
                float pc = __expf(a2 - mc) * isc * f2, ps = __expf(mnn - a2) * iss * f2;
                float v0 = __uint_as_float(w2 << 16);
                float v1 = __uint_as_float(w2 & 0xffff0000u);
                aC0 += v0 * pc; aC1 += v1 * pc; aS0 += v0 * ps; aS1 += v1 * ps;
            }
            {
                float pc = __expf(a3 - mc) * isc * f3, ps = __expf(mnn - a3) * iss * f3;
                float v0 = __uint_as_float(w3 << 16);
                float v1 = __uint_as_float(w3 & 0xffff0000u);
                aC0 += v0 * pc; aC1 += v1 * pc; aS0 += v0 * ps; aS1 += v1 * ps;
            }
        }
    } else {
        // slow: original CSR walk (rare)
        int b2 = 0;
        for (int ts = 0; ts <= t_tar; ++ts) {
            const int beg = offs[ts * (N_NODES + 1) + node];
            const int end = offs[ts * (N_NODES + 1) + node + 1];
            const int* __restrict__ sb = srcbuf + (size_t)ts * E_PER_T;
            for (int j = beg; j < end; ++j) {
                int idx = b2 + (j - beg);
                float a; size_t gaddr;
                if (idx < CAP) {
                    a = lg[idx][h2];
                    gaddr = (size_t)sx[idx] * HID;
                } else {
                    int src = sb[j];
                    gaddr = ((size_t)ts * N_NODES + src) * HID;
                    unsigned qd = *(const unsigned*)(Qt + (size_t)node * HID + 2 * lane);
                    unsigned kd = *(const unsigned*)(Kall + gaddr + 2 * lane);
                    float p = __uint_as_float(qd << 16) * __uint_as_float(kd << 16)
                            + __uint_as_float(qd & 0xffff0000u) * __uint_as_float(kd & 0xffff0000u);
                    p += __shfl_xor(p, 1);
                    p += __shfl_xor(p, 2);
                    p += __shfl_xor(p, 4);
                    a = p * 0.25f;
                }
                float pc = __expf(a - mc) * isc;
                float ps = __expf(mnn - a) * iss;
                unsigned v2 = *(const unsigned*)(Vall + gaddr + 2 * lane);
                float v0 = __uint_as_float(v2 << 16);
                float v1 = __uint_as_float(v2 & 0xffff0000u);
                aC0 += v0 * pc; aC1 += v1 * pc;
                aS0 += v0 * ps; aS1 += v1 * ps;
            }
            b2 += end - beg;
        }
    }
    size_t bidx = (size_t)node * HID + 2 * lane;
    *(unsigned*)(hat_c + bidx) = (unsigned)f2bf(aC0) | ((unsigned)f2bf(aC1) << 16);
    *(unsigned*)(hat_s + bidx) = (unsigned)f2bf(aS0) | ((unsigned)f2bf(aS1) << 16);
}

// ---------------------------------------------------------------------------
// FFN via MFMA, ALL t (blockIdx.y = t), branches parallel across waves,
// 32-node tile. hat read as bf16 (normal loads, L2/L3-resident); out written
// with nt stores (no L2 pollution). 32KB LDS, 5 blocks/CU.
// ---------------------------------------------------------------------------
__global__ __launch_bounds__(256, 5) void ffn_out_kernel(
    const u16* __restrict__ hat_c_all, const u16* __restrict__ hat_s_all,
    const float* __restrict__ x,
    const float* __restrict__ ln_s, const float* __restrict__ ln_b,
    const u16* __restrict__ W1T, const float* __restrict__ b1,
    const u16* __restrict__ W2T, const float* __restrict__ b2,
    float* __restrict__ out)
{
    __shared__ char ldsbuf[32768];
    u16* hnS = (u16*)ldsbuf;                 // [2][32*128] bf16 (16 KB)
    u16* chS = (u16*)(ldsbuf + 16384);       // [2][2][32*64] bf16 (16 KB)
    float* rS = (float*)ldsbuf;              // [2][32][128] f32 overlay (32 KB)

    const int t_tar = blockIdx.y;
    const int n0 = blockIdx.x * 32;
    const int tid = threadIdx.x;
    const size_t NHID = (size_t)N_NODES * HID;
    const u16* __restrict__ hat_c = hat_c_all + (size_t)t_tar * NHID;
    const u16* __restrict__ hat_s = hat_s_all + (size_t)t_tar * NHID;
    const float* __restrict__ xt = x + (size_t)t_tar * NHID;
    const size_t TS = (size_t)T_WIN * N_NODES * HID;
    const size_t outbase = (size_t)t_tar * NHID;

    const int lane = tid & 63;
    const int wave = tid >> 6;
    const int br   = wave >> 1;          // GEMM branch: 0 causal, 1 spurious
    const int wv   = wave & 1;           // wave-within-branch
    const int l15 = lane & 15, l4 = lane >> 4;
    const f32x4 z4 = {0.f, 0.f, 0.f, 0.f};

    // LN mapping: brL = tid>>7 (== br), 4 threads/row, 32 cols each
    const int brL = tid >> 7;
    const int rowL = (tid & 127) >> 2, qL = tid & 3;
    const int nL = n0 + rowL;
    const u16* __restrict__ hatL = brL ? hat_s : hat_c;

    float v[32];   // pre-LN row segment (hat [+x]) -- LIVE through GEMMs

    // ---- LayerNorm (hat bf16 + x f32, normal loads) ----
    {
        float s = 0.f, s2 = 0.f;
        if (nL < N_NODES) {
            const uint4* hp = (const uint4*)(hatL + (size_t)nL * 128 + qL * 32);
            const float4* xp = (const float4*)(xt + (size_t)nL * 128 + qL * 32);
#pragma unroll
            for (int i = 0; i < 4; ++i) {          // 8 cols per iter
                uint4 hu = hp[i];
                const unsigned* pu = (const unsigned*)&hu;
                float hv[8];
#pragma unroll
                for (int j = 0; j < 4; ++j) {
                    hv[2 * j]     = bf2f((u16)(pu[j] & 0xffffu));
                    hv[2 * j + 1] = bf2f((u16)(pu[j] >> 16));
                }
                if (brL == 0) {
                    float4 xa = xp[2 * i], xb = xp[2 * i + 1];
                    hv[0] += xa.x; hv[1] += xa.y; hv[2] += xa.z; hv[3] += xa.w;
                    hv[4] += xb.x; hv[5] += xb.y; hv[6] += xb.z; hv[7] += xb.w;
                }
#pragma unroll
                for (int j = 0; j < 8; ++j) {
                    v[8 * i + j] = hv[j];
                    s  += hv[j];
                    s2 += hv[j] * hv[j];
                }
            }
        } else {
#pragma unroll
            for (int i = 0; i < 32; ++i) v[i] = 0.f;
        }
        s  += __shfl_xor(s, 1);  s  += __shfl_xor(s, 2);
        s2 += __shfl_xor(s2, 1); s2 += __shfl_xor(s2, 2);
        float mu  = s * (1.f / 128.f);
        float var = s2 * (1.f / 128.f) - mu * mu;
        float rstd = rsqrtf(var + 1e-5f);
        const int sbase = brL * 4096 + rowL * 128;
#pragma unroll
        for (int i = 0; i < 4; ++i) {
            uint4 uh; unsigned* ph = (unsigned*)&uh;
#pragma unroll
            for (int j = 0; j < 4; ++j) {
                int c0 = qL * 32 + i * 8 + 2 * j;
                float h0 = (v[i * 8 + 2 * j]     - mu) * rstd * ln_s[c0]     + ln_b[c0];
                float h1 = (v[i * 8 + 2 * j + 1] - mu) * rstd * ln_s[c0 + 1] + ln_b[c0 + 1];
                if (nL >= N_NODES) { h0 = 0.f; h1 = 0.f; }
                ph[j] = (unsigned)f2bf(h0) | ((unsigned)f2bf(h1) << 16);
            }
            int ch = (qL * 4 + i) ^ (rowL & 15);
            *(uint4*)&hnS[sbase + ch * 8] = uh;
        }
    }
    __syncthreads();

    // ---- chunked GEMM1 -> GELU -> GEMM2 (K-fused, dbuf chS) ----
    f32x4 a2[2][4];
#pragma unroll
    for (int m = 0; m < 2; ++m)
#pragma unroll
        for (int n = 0; n < 4; ++n) a2[m][n] = z4;

#pragma unroll
    for (int cc = 0; cc < 4; ++cc) {
        f32x4 a1[2][2];
#pragma unroll
        for (int m = 0; m < 2; ++m)
#pragma unroll
            for (int n = 0; n < 2; ++n) a1[m][n] = z4;
#pragma unroll
        for (int ks = 0; ks < 4; ++ks) {
            const int ch = (ks * 4 + l4) ^ l15;
            bf16x8 af[2];
#pragma unroll
            for (int m = 0; m < 2; ++m)
                af[m] = *(const bf16x8*)&hnS[br * 4096 + (m * 16 + l15) * 128 + ch * 8];
#pragma unroll
            for (int n = 0; n < 2; ++n) {
                bf16x8 bfr = *(const bf16x8*)(W1T
                    + (size_t)(cc * 64 + wv * 32 + n * 16 + l15) * 128 + ks * 32 + l4 * 8);
#pragma unroll
                for (int m = 0; m < 2; ++m)
                    a1[m][n] = mfma16(af[m], bfr, a1[m][n]);
            }
        }
        // bias + exact GELU -> swizzled bf16 chunk tile
        u16* chw = chS + ((cc & 1) * 2 + br) * (32 * 64);
#pragma unroll
        for (int n = 0; n < 2; ++n) {
            int cl = wv * 32 + n * 16 + l15;        // local col 0..63
            float bb = b1[cc * 64 + cl];
#pragma unroll
            for (int m = 0; m < 2; ++m)
#pragma unroll
                for (int j = 0; j < 4; ++j) {
                    int r = m * 16 + l4 * 4 + j;
                    float zz = a1[m][n][j] + bb;
                    float g = 0.5f * zz * (1.f + erff(zz * 0.70710678118654752f));
                    chw[r * 64 + (((cl >> 3) ^ (r & 7)) * 8) + (cl & 7)] = f2bf(g);
                }
        }
        __syncthreads();
        // GEMM2 partial: K-slice cc*64..cc*64+63
        const u16* chr = chS + ((cc & 1) * 2 + br) * (32 * 64);
#pragma unroll
        for (int ks2 = 0; ks2 < 2; ++ks2) {
            const int ch8 = (ks2 * 4 + l4) ^ (l15 & 7);
            bf16x8 af[2];
#pragma unroll
            for (int m = 0; m < 2; ++m)
                af[m] = *(const bf16x8*)&chr[(m * 16 + l15) * 64 + ch8 * 8];
#pragma unroll
            for (int n = 0; n < 4; ++n) {
                bf16x8 bfr = *(const bf16x8*)(W2T
                    + (size_t)(wv * 64 + n * 16 + l15) * 256 + cc * 64 + ks2 * 32 + l4 * 8);
#pragma unroll
                for (int m = 0; m < 2; ++m)
                    a2[m][n] = mfma16(af[m], bfr, a2[m][n]);
            }
        }
    }
    __syncthreads();   // hnS + chS now dead -> rS overlay is safe

    // ---- r = a2 + b2 -> LDS (XOR-swizzled fp32) ----
#pragma unroll
    for (int n = 0; n < 4; ++n) {
        int c = wv * 64 + n * 16 + l15;
        float bb = b2[c];
#pragma unroll
        for (int m = 0; m < 2; ++m)
#pragma unroll
            for (int j = 0; j < 4; ++j) {
                int r = m * 16 + l4 * 4 + j;
                rS[br * 4096 + r * 128 + (c ^ ((r & 7) << 2))] = a2[m][n][j] + bb;
            }
    }
    __syncthreads();

    // ---- LN threads: fold val = v + r into rS in place ----
    {
        const int swzL = (rowL & 7) << 2;
#pragma unroll
        for (int i = 0; i < 8; ++i) {
            int coff = brL * 4096 + rowL * 128 + ((qL * 32 + i * 4) ^ swzL);
            float4 rv = *(const float4*)&rS[coff];
            rv.x += v[4 * i];     rv.y += v[4 * i + 1];
            rv.z += v[4 * i + 2]; rv.w += v[4 * i + 3];
            *(float4*)&rS[coff] = rv;
        }
    }
    __syncthreads();

    // ---- streaming nt stores: fully contiguous (1KB/wave/instr) ----
    {
        const int nrows = N_NODES - n0;   // valid rows in tile (<=32 means tail)
        float* o0 = out + outbase + (size_t)n0 * 128;
        float* o1 = out + TS + outbase + (size_t)n0 * 128;
        float* o2 = out + 2 * TS + outbase + (size_t)n0 * 128;
#pragma unroll
        for (int it = 0; it < 4; ++it) {
            int lin = it * 1024 + tid * 4;
            int row = lin >> 7, col = lin & 127;
            int sw  = col ^ ((row & 7) << 2);
            if (row < nrows) {
                f32x4 cv = *(const f32x4*)&rS[row * 128 + sw];
                f32x4 sv = *(const f32x4*)&rS[4096 + row * 128 + sw];
                ntstore4(&o1[lin], cv);
                ntstore4(&o2[lin], sv);
                ntstore4(&o0[lin], cv + sv);
            }
        }
    }
}

extern "C" void kernel_launch(void* const* d_in, const int* in_sizes, int n_in,
                              void* d_out, int out_size, void* d_ws, size_t ws_size,
                              hipStream_t stream) {
    const float* x    = (const float*)d_in[0];
    const int*   ei   = (const int*)  d_in[1];
    const float* Wq   = (const float*)d_in[2];
    const float* bq   = (const float*)d_in[3];
    const float* Wk   = (const float*)d_in[4];
    const float* bk   = (const float*)d_in[5];
    const float* Wv   = (const float*)d_in[6];
    const float* bv   = (const float*)d_in[7];
    const float* ln_s = (const float*)d_in[8];
    const float* ln_b = (const float*)d_in[9];
    const float* W1   = (const float*)d_in[10];
    const float* b1   = (const float*)d_in[11];
    const float* W2   = (const float*)d_in[12];
    const float* b2   = (const float*)d_in[13];
    float* out = (float*)d_out;

    // ---- Workspace layout (~197 MB) ----
    const size_t NHID = (size_t)N_NODES * HID;  // 6,400,000
    char* p = (char*)d_ws;
    auto alloc = [&p](size_t bytes) -> void* {
        void* r = (void*)p;
        p += (bytes + 255) & ~(size_t)255;
        return r;
    };
    u16* hat_c = (u16*)alloc(3 * NHID * 2);   // [t][N][HID] bf16
    u16* hat_s = (u16*)alloc(3 * NHID * 2);
    int* offs    = (int*)alloc((size_t)T_WIN * (N_NODES + 1) * 4);
    int* cursor  = (int*)alloc((size_t)T_WIN * N_NODES * 4);
    int* srcbuf  = (int*)alloc((size_t)T_WIN * E_PER_T * 4);
    u16* WqTh = (u16*)alloc(128 * 128 * 2);
    u16* WqTl = (u16*)alloc(128 * 128 * 2);
    u16* WkTh = (u16*)alloc(128 * 128 * 2);
    u16* WkTl = (u16*)alloc(128 * 128 * 2);
    u16* WvTh = (u16*)alloc(128 * 128 * 2);
    u16* WvTl = (u16*)alloc(128 * 128 * 2);
    u16* W1T  = (u16*)alloc(128 * 256 * 2);
    u16* W2T  = (u16*)alloc(256 * 128 * 2);
    u16* Qall = (u16*)alloc(3 * NHID * 2);
    u16* Kall = (u16*)alloc(3 * NHID * 2);
    u16* Vall = (u16*)alloc(3 * NHID * 2);

    const int PROJ_BLOCKS = (N_NODES + 63) / 64;          // 782
    const int FFN_BLOCKS  = (N_NODES + 31) / 32;          // 1563
    const int NODE_BLOCKS = (N_NODES + 3) / 4;            // 12500
    const int TN_BLOCKS   = (T_WIN * N_NODES + 255) / 256;
    const int TE_BLOCKS   = (T_WIN * E_PER_T + 255) / 256;

    // ---- weight prep (one dispatch) ----
    {
        dim3 wg(128, 5);
        wprep_kernel<<<wg, 256, 0, stream>>>(
            Wq, Wk, Wv, W1, W2,
            WqTh, WqTl, WkTh, WkTl, WvTh, WvTl, W1T, W2T);
    }

    // ---- CSR build ----
    zero_counts_kernel<<<TN_BLOCKS, 256, 0, stream>>>(cursor);
    hist_kernel<<<TE_BLOCKS, 256, 0, stream>>>(ei, cursor);
    scan_kernel<<<T_WIN, 1024, 0, stream>>>(cursor, offs);
    copy_cursor_kernel<<<TN_BLOCKS, 256, 0, stream>>>(offs, cursor);
    fill_kernel<<<TE_BLOCKS, 256, 0, stream>>>(ei, cursor, srcbuf);

    // ---- all projections (Q/K/V x 3 ts) in one dispatch ----
    {
        dim3 pg(PROJ_BLOCKS, 9);
        project_all_kernel<<<pg, 256, 0, stream>>>(
            x, WqTh, WqTl, bq, WkTh, WkTl, bk, WvTh, WvTl, bv,
            Qall, Kall, Vall);
    }

    // ---- attention, all t in one dispatch ----
    {
        dim3 ag(NODE_BLOCKS, T_WIN);
        attn_fused_kernel<<<ag, 256, 0, stream>>>(
            Qall, Kall, Vall, offs, srcbuf, hat_c, hat_s);
    }

    // ---- FFN + output, all t in one dispatch ----
    {
        dim3 fg(FFN_BLOCKS, T_WIN);
        ffn_out_kernel<<<fg, 256, 0, stream>>>(
            hat_c, hat_s, x, ln_s, ln_b, W1T, b1, W2T, b2, out);
    }
}